// Round 6
// baseline (283.392 us; speedup 1.0000x reference)
//
#include <hip/hip_runtime.h>
#include <hip/hip_bf16.h>

#define PI_F 3.14159265f

// Flat index convention: state.reshape((2,)*16) => qubit q corresponds to
// flat bit j = 15 - q.  Circuit per layer (flat-bit gates):
//   Ry on all flat bits j (angle of qubit 15-j)
//   CNOT chain: (c=15,t=14),(14,13),...,(1,0),(0,15)
//   Rz on all flat bits
// Measurement: <Z_q> q=0,1,2  ->  flat bits 15,14,13.
//
// 2-pass structure (512KB/element state in d_ws, canonical st[f]=amp[f]):
//   P1 k_all (A-type, outer=f13..15, WRITE-only): generation with chain1 folded
//      (b_pre[j]=f_j^f_{j+1}, b_pre[14]=f14^f0^f15, b_pre[15]=f0^f15), Rz1,
//      Ry2(f13..15)+CN2(15->14),(14->13) folded ANALYTICALLY into a per-block
//      8-term kernel K[f0,f12] (those ops only touch outer bits + f0,f12
//      boundary couplings), Ry2(f0..12) applied in-trip, chain2 targets 12..0,
//      Rz2(f0..14), Ry3(1..12).  Trips: T3 -> T2 -> T1 -> T2 -> T3 (store).
//   P2 k_fin (B-type, outer=f10..12, READ-only): CN2(0->15), Rz2(f15),
//      Ry3{0,13,14,15}, measurement with CN3 transported:
//      Z_f15 -> parity(f0..f14); Z_f14 -> f14^f15; Z_f13 -> f13^f14^f15.
//      Rz3 dropped (diagonal, |amp|^2 invariant).
// Chunked at 256 elements (128MB) so the P1->P2 handoff is L3-resident.

__device__ __forceinline__ unsigned swz(unsigned l){ return l ^ ((l>>5)&31u); }

__device__ __forceinline__ void ry_pair(float2& A0, float2& A1, float c, float s){
    float2 a0=A0, a1=A1;
    A0 = make_float2(c*a0.x - s*a1.x, c*a0.y - s*a1.y);
    A1 = make_float2(s*a0.x + c*a1.x, s*a0.y + c*a1.y);
}

// ---------------- P1: full generation + layer2 + Ry3(1..12), write-only
__global__ __launch_bounds__(256) void k_all(const float* __restrict__ xg,
                                             const float* __restrict__ pg,
                                             float2* __restrict__ st)
{
    __shared__ float2 tile[8192];
    __shared__ float cA[16], sA[16], cB[16], sB[16], cC[16], sC[16], phz1[16], phz2[16];
    __shared__ float2 TK[32], D2[32];
    const int tid = threadIdx.x;
    const int b = blockIdx.x >> 3;
    const unsigned outer = blockIdx.x & 7u;        // f bits 13..15
    // ---- stage 1: angle tables
    if (tid < 16){
        int j = tid, q = 15 - j;
        float th = 0.5f*(xg[b*16+q]*PI_F + pg[q]);           // Ry1
        __sincosf(th, &sA[j], &cA[j]);
    } else if (tid < 32){
        int j = tid-16, q = 15 - j;
        float th = 0.5f*(xg[b*16+q]*PI_F + pg[32+q]);        // Ry2
        __sincosf(th, &sB[j], &cB[j]);
    } else if (tid < 48){
        int j = tid-32, q = 15 - j;
        float th = 0.5f*(xg[b*16+q]*PI_F + pg[64+q]);        // Ry3
        __sincosf(th, &sC[j], &cC[j]);
    } else if (tid < 64){
        int j = tid-48, q = 15 - j;
        phz1[j] = 0.5f*pg[16+q];                              // Rz1
    } else if (tid < 80){
        int j = tid-64, q = 15 - j;
        phz2[j] = 0.5f*pg[48+q];                              // Rz2
    }
    __syncthreads();
    // ---- stage 2: block-uniform tables TK (gen kernel) and D2 (Rz2 deltas)
    if (tid < 32){
        const unsigned o13 = outer&1u, o14=(outer>>1)&1u, o15=(outer>>2)&1u;
        const unsigned h13 = o13^o14, h14 = o14^o15, h15 = o15;   // pre-CNfront bits
        const int f0b = tid&1, f12b = (tid>>4)&1;
        float Kr=0.f, Ki=0.f;
        #pragma unroll
        for (int g=0; g<8; ++g){
            const unsigned g13=g&1u, g14=(g>>1)&1u, g15=(g>>2)&1u;
            float w;
            w  = (h13==g13)? cB[13] : (h13? sB[13] : -sB[13]);
            w *= (h14==g14)? cB[14] : (h14? sB[14] : -sB[14]);
            w *= (h15==g15)? cB[15] : (h15? sB[15] : -sB[15]);
            w *= (f12b^(int)g13)?        sA[12]:cA[12];
            w *= (g13^g14)?              sA[13]:cA[13];
            w *= ((int)g14^f0b^(int)g15)? sA[14]:cA[14];
            w *= (f0b^(int)g15)?         sA[15]:cA[15];
            float phg = (g13? phz1[13]:-phz1[13]) + (g14? phz1[14]:-phz1[14])
                      + (g15? phz1[15]:-phz1[15]);
            float sn,cs; __sincosf(phg,&sn,&cs);
            Kr += w*cs; Ki += w*sn;
        }
        float dphi = ((tid&1)?      phz1[0] :-phz1[0])
                   + (((tid>>1)&1)? phz1[1] :-phz1[1])
                   + (((tid>>2)&1)? phz1[10]:-phz1[10])
                   + (((tid>>3)&1)? phz1[11]:-phz1[11])
                   + (((tid>>4)&1)? phz1[12]:-phz1[12]);
        float sd,cd; __sincosf(dphi,&sd,&cd);
        TK[tid] = make_float2(cd*Kr - sd*Ki, cd*Ki + sd*Kr);
    } else if (tid < 64){
        const int ii = tid-32;
        float d = ((ii&1)?      phz2[0]:-phz2[0])
                + (((ii>>1)&1)? phz2[1]:-phz2[1])
                + (((ii>>2)&1)? phz2[2]:-phz2[2])
                + (((ii>>3)&1)? phz2[3]:-phz2[3])
                + (((ii>>4)&1)? phz2[4]:-phz2[4]);
        float sn,cs; __sincosf(d,&sn,&cs);
        D2[ii] = make_float2(cs,sn);
    }
    __syncthreads();
    const unsigned t = tid;                         // T3: t = f2..9
    float2* sp = st + ((size_t)b<<16);
    float2 a[32];
    // ---- T3 generation: i = {f0,f1,f10,f11,f12}
    {
        float phi_t = 0.f;
        #pragma unroll
        for (int j=2;j<10;j++) phi_t += ((t>>(j-2))&1u)? phz1[j] : -phz1[j];
        float Ety, Etx; __sincosf(phi_t, &Ety, &Etx);
        float base_t = 1.0f;
        #pragma unroll
        for (int j=2;j<9;j++){
            int v = (int)(((t>>(j-2)) ^ (t>>(j-1))) & 1u);   // b_pre[j]=f_j^f_{j+1}
            base_t *= v ? sA[j] : cA[j];
        }
        const int t0 = (int)(t&1u), t7 = (int)((t>>7)&1u);
        #pragma unroll
        for (int i=0;i<32;i++){
            const int i0=i&1, i1=(i>>1)&1, i2=(i>>2)&1, i3=(i>>3)&1, i4=(i>>4)&1;
            float pr = base_t;
            pr *= (i0^i1)? sA[0] :cA[0];
            pr *= (i1^t0)? sA[1] :cA[1];
            pr *= (t7^i2)? sA[9] :cA[9];
            pr *= (i2^i3)? sA[10]:cA[10];
            pr *= (i3^i4)? sA[11]:cA[11];
            const float2 w = TK[i];
            const float rx = Etx*w.x - Ety*w.y;
            const float ry = Etx*w.y + Ety*w.x;
            a[i] = make_float2(pr*rx, pr*ry);
        }
    }
    // Ry2(f0,f1): i bits 0,1 ; Ry2(f10,f11,f12): i bits 2,3,4
    #pragma unroll
    for (int j=0;j<32;j++){ if (j&1)  continue; ry_pair(a[j],a[j|1] ,cB[0] ,sB[0]);  }
    #pragma unroll
    for (int j=0;j<32;j++){ if (j&2)  continue; ry_pair(a[j],a[j|2] ,cB[1] ,sB[1]);  }
    #pragma unroll
    for (int j=0;j<32;j++){ if (j&4)  continue; ry_pair(a[j],a[j|4] ,cB[10],sB[10]); }
    #pragma unroll
    for (int j=0;j<32;j++){ if (j&8)  continue; ry_pair(a[j],a[j|8] ,cB[11],sB[11]); }
    #pragma unroll
    for (int j=0;j<32;j++){ if (j&16) continue; ry_pair(a[j],a[j|16],cB[12],sB[12]); }
    // CN2(13->12): control f13 = outer bit0 (uniform), target i bit4
    if (outer & 1u){
        #pragma unroll
        for (int j=0;j<32;j++){ if (j&16) continue; float2 tm=a[j]; a[j]=a[j|16]; a[j|16]=tm; }
    }
    // CN2(12->11): control i bit4, target i bit3
    #pragma unroll
    for (int j=0;j<32;j++){ if (j&8) continue; if ((j>>4)&1){ float2 tm=a[j]; a[j]=a[j|8]; a[j|8]=tm; } }
    // CN2(11->10): control i bit3, target i bit2
    #pragma unroll
    for (int j=0;j<32;j++){ if (j&4) continue; if ((j>>3)&1){ float2 tm=a[j]; a[j]=a[j|4]; a[j|4]=tm; } }
    // ---- transpose T3 -> T2
    #pragma unroll
    for (int i=0;i<32;i++) tile[swz((unsigned)(i&3) | (t<<2) | ((unsigned)(i>>2)<<10))] = a[i];
    __syncthreads();
    #pragma unroll
    for (int i=0;i<32;i++) a[i] = tile[swz((t&31u) | ((unsigned)i<<5) | ((t>>5)<<10))];
    // T2: f5..9 = i; f0..4 = t&31; f10..12 = t>>5
    // Ry2(f5..f9)
    #pragma unroll
    for (int qq=0;qq<5;qq++){
        const int bit = 1<<qq;
        const float c=cB[5+qq], s=sB[5+qq];
        #pragma unroll
        for (int j=0;j<32;j++){ if (j&bit) continue; ry_pair(a[j],a[j|bit],c,s); }
    }
    // CN2(10->9): control f10 = (t>>5)&1 (fixed), target i bit4
    if ((t>>5)&1u){
        #pragma unroll
        for (int j=0;j<32;j++){ if (j&16) continue; float2 tm=a[j]; a[j]=a[j|16]; a[j|16]=tm; }
    }
    // CN2(9->8),(8->7),(7->6),(6->5)
    #pragma unroll
    for (int qq=3;qq>=0;qq--){
        const int bit = 1<<qq;
        #pragma unroll
        for (int j=0;j<32;j++){ if (j&bit) continue; if ((j>>(qq+1))&1){ float2 tm=a[j]; a[j]=a[j|bit]; a[j|bit]=tm; } }
    }
    // ---- transpose T2 -> T1
    #pragma unroll
    for (int i=0;i<32;i++) tile[swz((t&31u) | ((unsigned)i<<5) | ((t>>5)<<10))] = a[i];
    __syncthreads();
    #pragma unroll
    for (int i=0;i<32;i++) a[i] = tile[swz((unsigned)i | (t<<5))];
    // T1: f0..4 = i; f5..12 = t; f13..15 = outer
    // Ry2(f2,f3,f4): i bits 2,3,4
    #pragma unroll
    for (int j=0;j<32;j++){ if (j&4)  continue; ry_pair(a[j],a[j|4] ,cB[2],sB[2]); }
    #pragma unroll
    for (int j=0;j<32;j++){ if (j&8)  continue; ry_pair(a[j],a[j|8] ,cB[3],sB[3]); }
    #pragma unroll
    for (int j=0;j<32;j++){ if (j&16) continue; ry_pair(a[j],a[j|16],cB[4],sB[4]); }
    // CN2(5->4): control f5 = t bit0, target i bit4
    if (t & 1u){
        #pragma unroll
        for (int j=0;j<32;j++){ if (j&16) continue; float2 tm=a[j]; a[j]=a[j|16]; a[j|16]=tm; }
    }
    // CN2(4->3),(3->2),(2->1),(1->0)
    #pragma unroll
    for (int qq=3;qq>=0;qq--){
        const int bit = 1<<qq;
        #pragma unroll
        for (int j=0;j<32;j++){ if (j&bit) continue; if ((j>>(qq+1))&1){ float2 tm=a[j]; a[j]=a[j|bit]; a[j|bit]=tm; } }
    }
    // Rz2 on flat bits 0..14 (f15 deferred to k_fin, after CN2(0->15))
    {
        float ab = 0.0f;
        #pragma unroll
        for (int j=5;j<13;j++) ab += ((t>>(j-5))&1u)? phz2[j] : -phz2[j];
        ab += (outer&1u)?      phz2[13] : -phz2[13];
        ab += ((outer>>1)&1u)? phz2[14] : -phz2[14];
        float Eay, Eax; __sincosf(ab, &Eay, &Eax);
        #pragma unroll
        for (int i=0;i<32;i++){
            const float2 d = D2[i];
            const float rx = Eax*d.x - Eay*d.y;
            const float ry = Eax*d.y + Eay*d.x;
            const float2 v = a[i];
            a[i] = make_float2(v.x*rx - v.y*ry, v.x*ry + v.y*rx);
        }
    }
    // Ry3(f1..f4): i bits 1..4
    #pragma unroll
    for (int qq=1;qq<=4;qq++){
        const int bit = 1<<qq;
        const float c=cC[qq], s=sC[qq];
        #pragma unroll
        for (int j=0;j<32;j++){ if (j&bit) continue; ry_pair(a[j],a[j|bit],c,s); }
    }
    // ---- transpose T1 -> T2: Ry3(f5..f9)
    __syncthreads();
    #pragma unroll
    for (int i=0;i<32;i++) tile[swz((unsigned)i | (t<<5))] = a[i];
    __syncthreads();
    #pragma unroll
    for (int i=0;i<32;i++) a[i] = tile[swz((t&31u) | ((unsigned)i<<5) | ((t>>5)<<10))];
    #pragma unroll
    for (int qq=0;qq<5;qq++){
        const int bit = 1<<qq;
        const float c=cC[5+qq], s=sC[5+qq];
        #pragma unroll
        for (int j=0;j<32;j++){ if (j&bit) continue; ry_pair(a[j],a[j|bit],c,s); }
    }
    // ---- transpose T2 -> T3: Ry3(f10..f12) + coalesced store
    #pragma unroll
    for (int i=0;i<32;i++) tile[swz((t&31u) | ((unsigned)i<<5) | ((t>>5)<<10))] = a[i];
    __syncthreads();
    #pragma unroll
    for (int i=0;i<32;i++) a[i] = tile[swz((unsigned)(i&3) | (t<<2) | ((unsigned)(i>>2)<<10))];
    // T3: f0,f1 = i&3; f2..9 = t; f10..12 = i>>2
    #pragma unroll
    for (int j=0;j<32;j++){ if (j&4)  continue; ry_pair(a[j],a[j|4] ,cC[10],sC[10]); }
    #pragma unroll
    for (int j=0;j<32;j++){ if (j&8)  continue; ry_pair(a[j],a[j|8] ,cC[11],sC[11]); }
    #pragma unroll
    for (int j=0;j<32;j++){ if (j&16) continue; ry_pair(a[j],a[j|16],cC[12],sC[12]); }
    #pragma unroll
    for (int u=0;u<8;u++){
        unsigned fb = (t<<2) | ((unsigned)u<<10) | (outer<<13);
        float4* d4 = (float4*)(sp + fb);
        d4[0]=make_float4(a[4*u+0].x,a[4*u+0].y,a[4*u+1].x,a[4*u+1].y);
        d4[1]=make_float4(a[4*u+2].x,a[4*u+2].y,a[4*u+3].x,a[4*u+3].y);
    }
}

// ---------------- P2 k_fin (B-type, outer = f10..12, READ, no LDS tile):
// CN2(0->15), Rz2(f15), Ry3{0,13,14,15}, measurement with CN3 transported:
//   <Z_q0> mask = parity(f0..f14); <Z_q1> = f14^f15; <Z_q2> = f13^f14^f15.
__global__ __launch_bounds__(256) void k_fin(const float* __restrict__ xg,
                                             const float* __restrict__ pg,
                                             const float2* __restrict__ st,
                                             float* __restrict__ outg)
{
    __shared__ float cN[16], sN[16];
    __shared__ float snp, csp;
    __shared__ float red[4][3];
    const int tid = threadIdx.x;
    const int b = blockIdx.x >> 3;
    const unsigned outer = blockIdx.x & 7u;        // f bits 10..12
    if (tid < 16){
        int j=tid, q=15-j;
        float th = 0.5f*(xg[b*16+q]*PI_F + pg[64 + q]);      // Ry3
        float s,c; __sincosf(th,&s,&c);
        cN[j]=c; sN[j]=s;
    }
    if (tid==16){ float phi = 0.5f*pg[48 + 0]; float s,c; __sincosf(phi,&s,&c); snp=s; csp=c; }  // Rz2(f15)=qubit0
    __syncthreads();
    const unsigned t = tid;
    const float2* sp = st + ((size_t)b<<16);
    float2 a[32];
    // T3 load (B-type): f = (i&3) | (t<<2) | (outer<<10) | ((i>>2)<<13)
    #pragma unroll
    for (int u=0;u<8;u++){
        unsigned fb = (t<<2) | (outer<<10) | ((unsigned)u<<13);
        const float4* s4 = (const float4*)(sp + fb);
        float4 v0=s4[0], v1=s4[1];
        a[4*u+0]=make_float2(v0.x,v0.y); a[4*u+1]=make_float2(v0.z,v0.w);
        a[4*u+2]=make_float2(v1.x,v1.y); a[4*u+3]=make_float2(v1.z,v1.w);
    }
    // CN2(0->15): control f0 = i bit0, target f15 = i bit4
    #pragma unroll
    for (int j=0;j<32;j++){ if (j&16) continue; if (j&1){ float2 tm=a[j]; a[j]=a[j|16]; a[j|16]=tm; } }
    // Rz2(f15): phase +-phi by i bit4
    #pragma unroll
    for (int j=0;j<32;j++){
        float sn = ((j>>4)&1)? snp : -snp;
        float2 v=a[j];
        a[j]=make_float2(v.x*csp - v.y*sn, v.x*sn + v.y*csp);
    }
    // Ry3(f0): i bit0 ; Ry3(f13,f14,f15): i bits 2,3,4
    #pragma unroll
    for (int j=0;j<32;j++){ if (j&1)  continue; ry_pair(a[j],a[j|1] ,cN[0] ,sN[0]);  }
    #pragma unroll
    for (int j=0;j<32;j++){ if (j&4)  continue; ry_pair(a[j],a[j|4] ,cN[13],sN[13]); }
    #pragma unroll
    for (int j=0;j<32;j++){ if (j&8)  continue; ry_pair(a[j],a[j|8] ,cN[14],sN[14]); }
    #pragma unroll
    for (int j=0;j<32;j++){ if (j&16) continue; ry_pair(a[j],a[j|16],cN[15],sN[15]); }
    // measurement sums; f0=i0, f1=i1, f2..9=t, f10..12=outer, f13=i2, f14=i3, f15=i4
    const int pto = (__popc(t) + __popc(outer)) & 1;   // parity(f2..f12)
    float v0=0.f, v1=0.f, v2=0.f;
    #pragma unroll
    for (int i=0;i<32;i++){
        const int i0=i&1, i1=(i>>1)&1, i2=(i>>2)&1, i3=(i>>3)&1, i4=(i>>4)&1;
        const float pr = a[i].x*a[i].x + a[i].y*a[i].y;
        v0 += (i0^i1^i2^i3^pto)? -pr : pr;   // parity(f0..f14)
        v1 += (i3^i4)?           -pr : pr;   // f14^f15
        v2 += (i2^i3^i4)?        -pr : pr;   // f13^f14^f15
    }
    #pragma unroll
    for (int off=32; off>0; off>>=1){
        v0 += __shfl_down(v0, off);
        v1 += __shfl_down(v1, off);
        v2 += __shfl_down(v2, off);
    }
    const int wv = tid>>6, ln = tid&63;
    if (ln==0){ red[wv][0]=v0; red[wv][1]=v1; red[wv][2]=v2; }
    __syncthreads();
    if (tid<3){
        float s = red[0][tid]+red[1][tid]+red[2][tid]+red[3][tid];
        atomicAdd(&outg[b*3+tid], s);
    }
}

extern "C" void kernel_launch(void* const* d_in, const int* in_sizes, int n_in,
                              void* d_out, int out_size, void* d_ws, size_t ws_size,
                              hipStream_t stream)
{
    const float* x = (const float*)d_in[0];
    const float* params = (const float*)d_in[1];
    float* out = (float*)d_out;
    float2* st = (float2*)d_ws;
    const int B = in_sizes[0] / 16;

    hipMemsetAsync(d_out, 0, (size_t)out_size*sizeof(float), stream);

    const size_t per = (size_t)65536 * sizeof(float2);   // 512 KB per batch element
    int chunk = (int)(ws_size / per);
    if (chunk > 256) chunk = 256;                        // 128 MB working set -> L3-resident
    if (chunk < 1) chunk = 1;
    if (chunk > B) chunk = B;
    for (int b0=0; b0<B; b0+=chunk){
        const int nb = (B-b0 < chunk) ? (B-b0) : chunk;
        dim3 gr(nb*8), bl(256);
        const float* xb = x + (size_t)b0*16;
        float* ob = out + (size_t)b0*3;
        hipLaunchKernelGGL(k_all, gr, bl, 0, stream, xb, params, st);
        hipLaunchKernelGGL(k_fin, gr, bl, 0, stream, xb, params, st, ob);
    }
}

// Round 8
// 224.051 us; speedup vs baseline: 1.2649x; 1.2649x over previous
//
#include <hip/hip_runtime.h>
#include <hip/hip_bf16.h>

#define PI_F 3.14159265f

// Flat index convention: state.reshape((2,)*16) => qubit q <-> flat bit j = 15-q.
// Per layer: Ry(all f), CNOT chain (15->14),(14->13),...,(1->0),(0->15), Rz(all f).
// Measurement <Z_q> q=0,1,2 -> flat bits 15,14,13.
//
// 2-pass structure (512KB/element canonical state st[f] in d_ws):
//   P1 k_all (outer=f13..15, 512 thr, 16 amps/thr, WRITE-only):
//     - generation with chain1 folded + Rz1; Ry2(13..15)+CN2(15->14),(14->13)
//       folded analytically into K4[f0,f12] (8-term sum, R6-verified)
//     - 4 compute trips with overlapping 4-bit spans (A:f9..12, B:f6..9,
//       C:f3..6, D:f0..3) covering Ry2(0..12), CN2(13->12..1->0), Rz2(0..14),
//       Ry3(1..12); commutation checked per gate.
//     - store trip: swizzle-aware dense re-read (swz(idx+k)=swz(idx)^k),
//       32B-contiguous stores.
//   P2 k_fin (outer=f10..12, 256 thr, READ-only, verbatim-verified):
//     CN2(0->15), Rz2(f15), Ry3{0,13,14,15}, measurement with CN3 transported:
//     Z_f15 -> parity(f0..f14); Z_f14 -> f14^f15; Z_f13 -> f13^f14^f15; Rz3 dropped.
// Chunked at 256 elements (128MB) so the P1->P2 handoff is L3-resident.

__device__ __forceinline__ unsigned swz(unsigned l){ return l ^ ((l>>5)&31u); }

__device__ __forceinline__ float2 cmul(float2 a, float2 b){
    return make_float2(a.x*b.x - a.y*b.y, a.x*b.y + a.y*b.x);
}

__device__ __forceinline__ void ry_pair(float2& A0, float2& A1, float c, float s){
    float2 a0=A0, a1=A1;
    A0 = make_float2(c*a0.x - s*a1.x, c*a0.y - s*a1.y);
    A1 = make_float2(s*a0.x + c*a1.x, s*a0.y + c*a1.y);
}

// ---------------- P1: full generation + layer2(- (0->15),Rz2(f15)) + Ry3(1..12)
__global__ __launch_bounds__(512, 4) void k_all(const float* __restrict__ xg,
                                                const float* __restrict__ pg,
                                                float2* __restrict__ st)
{
    __shared__ float2 tile[8192];
    __shared__ float cA[16], sA[16], cB[16], sB[16], cC[16], sC[16], phz1[16], phz2[16];
    __shared__ float2 K4[4], D1[16], E2A[16], E2B[8], E2C[8], E2D[8];
    const int tid = threadIdx.x;
    const int b = blockIdx.x >> 3;
    const unsigned outer = blockIdx.x & 7u;        // f13..15 (post-fold basis)

    // ---- stage 1: angle tables
    if (tid < 16){
        int j = tid, q = 15 - j;
        float th = 0.5f*(xg[b*16+q]*PI_F + pg[q]);           // Ry1
        __sincosf(th, &sA[j], &cA[j]);
    } else if (tid < 32){
        int j = tid-16, q = 15 - j;
        float th = 0.5f*(xg[b*16+q]*PI_F + pg[32+q]);        // Ry2
        __sincosf(th, &sB[j], &cB[j]);
    } else if (tid < 48){
        int j = tid-32, q = 15 - j;
        float th = 0.5f*(xg[b*16+q]*PI_F + pg[64+q]);        // Ry3
        __sincosf(th, &sC[j], &cC[j]);
    } else if (tid < 64){
        int j = tid-48, q = 15 - j;
        phz1[j] = 0.5f*pg[16+q];                              // Rz1
    } else if (tid < 80){
        int j = tid-64, q = 15 - j;
        phz2[j] = 0.5f*pg[48+q];                              // Rz2
    }
    __syncthreads();
    // ---- stage 2: block-uniform tables
    if (tid < 4){
        // K4[(f0<<1)|f12]: Ry2(13..15)+CN2(15->14),(14->13) analytic fold (R6-verified)
        const unsigned o13=outer&1u, o14=(outer>>1)&1u, o15=(outer>>2)&1u;
        const unsigned h13=o13^o14, h14=o14^o15, h15=o15;
        const int f0b=(tid>>1)&1, f12b=tid&1;
        float Kr=0.f, Ki=0.f;
        #pragma unroll
        for (int g=0; g<8; ++g){
            const unsigned g13=g&1u, g14=(g>>1)&1u, g15=(g>>2)&1u;
            float w;
            w  = (h13==g13)? cB[13] : (h13? sB[13] : -sB[13]);
            w *= (h14==g14)? cB[14] : (h14? sB[14] : -sB[14]);
            w *= (h15==g15)? cB[15] : (h15? sB[15] : -sB[15]);
            w *= (f12b^(int)g13)?          sA[12]:cA[12];
            w *= ((int)(g13^g14))?         sA[13]:cA[13];
            w *= ((int)g14^f0b^(int)g15)?  sA[14]:cA[14];
            w *= (f0b^(int)g15)?           sA[15]:cA[15];
            float phg = (g13? phz1[13]:-phz1[13]) + (g14? phz1[14]:-phz1[14])
                      + (g15? phz1[15]:-phz1[15]);
            float sn,cs; __sincosf(phg,&sn,&cs);
            Kr += w*cs; Ki += w*sn;
        }
        K4[tid] = make_float2(Kr,Ki);
    } else if (tid>=16 && tid<32){
        const int ii = tid-16;  // Rz1 deltas over f9..12
        float d=0.f;
        #pragma unroll
        for (int j=0;j<4;j++) d += ((ii>>j)&1)? phz1[9+j]:-phz1[9+j];
        float sn,cs; __sincosf(d,&sn,&cs); D1[ii]=make_float2(cs,sn);
    } else if (tid>=32 && tid<48){
        const int ii = tid-32;  // Rz2 over f9..12
        float d=0.f;
        #pragma unroll
        for (int j=0;j<4;j++) d += ((ii>>j)&1)? phz2[9+j]:-phz2[9+j];
        float sn,cs; __sincosf(d,&sn,&cs); E2A[ii]=make_float2(cs,sn);
    } else if (tid>=48 && tid<56){
        const int ii = tid-48;  // Rz2 over f6..8
        float d=0.f;
        #pragma unroll
        for (int j=0;j<3;j++) d += ((ii>>j)&1)? phz2[6+j]:-phz2[6+j];
        float sn,cs; __sincosf(d,&sn,&cs); E2B[ii]=make_float2(cs,sn);
    } else if (tid>=56 && tid<64){
        const int ii = tid-56;  // Rz2 over f3..5
        float d=0.f;
        #pragma unroll
        for (int j=0;j<3;j++) d += ((ii>>j)&1)? phz2[3+j]:-phz2[3+j];
        float sn,cs; __sincosf(d,&sn,&cs); E2C[ii]=make_float2(cs,sn);
    } else if (tid>=64 && tid<72){
        const int ii = tid-64;  // Rz2 over f0..2 + uniform f13,f14
        float d=0.f;
        #pragma unroll
        for (int j=0;j<3;j++) d += ((ii>>j)&1)? phz2[j]:-phz2[j];
        d += (outer&1u)?      phz2[13]:-phz2[13];
        d += ((outer>>1)&1u)? phz2[14]:-phz2[14];
        float sn,cs; __sincosf(d,&sn,&cs); E2D[ii]=make_float2(cs,sn);
    }
    __syncthreads();

    const unsigned t = tid;                 // trip A: t = f0..8 (9 bits)
    float2 a[16];
    // ---- Trip A generation: i = f9..12
    {
        float base_t = 1.0f;
        #pragma unroll
        for (int j=0;j<8;j++){
            int v = (int)(((t>>j)^(t>>(j+1)))&1u);           // b_pre[j]=f_j^f_{j+1}
            base_t *= v? sA[j]:cA[j];
        }
        float pht = 0.f;
        #pragma unroll
        for (int j=0;j<9;j++) pht += ((t>>j)&1u)? phz1[j]:-phz1[j];
        float Ety,Etx; __sincosf(pht,&Ety,&Etx);
        const float2 Et = make_float2(Etx,Ety);
        const unsigned t0 = t&1u;
        const float2 EK0 = cmul(Et, K4[t0<<1]);
        const float2 EK1 = cmul(Et, K4[(t0<<1)|1u]);
        const int t8 = (int)((t>>8)&1u);
        #pragma unroll
        for (int i=0;i<16;i++){
            const int i0=i&1, i1=(i>>1)&1, i2=(i>>2)&1, i3=(i>>3)&1;
            float pr = base_t;
            pr *= (t8^i0)? sA[8] :cA[8];                     // b_pre[8]=f8^f9
            pr *= (i0^i1)? sA[9] :cA[9];
            pr *= (i1^i2)? sA[10]:cA[10];
            pr *= (i2^i3)? sA[11]:cA[11];
            float2 w = cmul(D1[i], i3? EK1:EK0);
            a[i] = make_float2(pr*w.x, pr*w.y);
        }
    }
    // Trip A gates: i0=f9,i1=f10,i2=f11,i3=f12
    #pragma unroll
    for (int j=0;j<16;j++){ if (j&1)  continue; ry_pair(a[j],a[j|1] ,cB[9] ,sB[9]);  }
    #pragma unroll
    for (int j=0;j<16;j++){ if (j&2)  continue; ry_pair(a[j],a[j|2] ,cB[10],sB[10]); }
    #pragma unroll
    for (int j=0;j<16;j++){ if (j&4)  continue; ry_pair(a[j],a[j|4] ,cB[11],sB[11]); }
    #pragma unroll
    for (int j=0;j<16;j++){ if (j&8)  continue; ry_pair(a[j],a[j|8] ,cB[12],sB[12]); }
    if (outer & 1u){  // CN2(13->12): ctrl f13=o13 (uniform), tgt i3
        #pragma unroll
        for (int j=0;j<16;j++){ if (j&8) continue; float2 tm=a[j]; a[j]=a[j|8]; a[j|8]=tm; }
    }
    #pragma unroll
    for (int j=0;j<16;j++){ if (j&4) continue; if ((j>>3)&1){ float2 tm=a[j]; a[j]=a[j|4]; a[j|4]=tm; } } // (12->11)
    #pragma unroll
    for (int j=0;j<16;j++){ if (j&2) continue; if ((j>>2)&1){ float2 tm=a[j]; a[j]=a[j|2]; a[j|2]=tm; } } // (11->10)
    #pragma unroll
    for (int j=0;j<16;j++){ if (j&1) continue; if ((j>>1)&1){ float2 tm=a[j]; a[j]=a[j|1]; a[j|1]=tm; } } // (10->9)
    #pragma unroll
    for (int i=0;i<16;i++) a[i] = cmul(a[i], E2A[i]);        // Rz2(f9..12)
    #pragma unroll
    for (int j=0;j<16;j++){ if (j&2)  continue; ry_pair(a[j],a[j|2] ,cC[10],sC[10]); }
    #pragma unroll
    for (int j=0;j<16;j++){ if (j&4)  continue; ry_pair(a[j],a[j|4] ,cC[11],sC[11]); }
    #pragma unroll
    for (int j=0;j<16;j++){ if (j&8)  continue; ry_pair(a[j],a[j|8] ,cC[12],sC[12]); }
    // ---- transpose A -> B
    #pragma unroll
    for (int i=0;i<16;i++) tile[swz(t | ((unsigned)i<<9))] = a[i];
    __syncthreads();
    #pragma unroll
    for (int i=0;i<16;i++) a[i] = tile[swz((t&63u) | ((unsigned)i<<6) | ((t>>6)<<10))];
    // Trip B: i0=f6,i1=f7,i2=f8,i3=f9 ; t&63=f0..5, t>>6=f10..12
    #pragma unroll
    for (int j=0;j<16;j++){ if (j&1)  continue; ry_pair(a[j],a[j|1] ,cB[6],sB[6]); }
    #pragma unroll
    for (int j=0;j<16;j++){ if (j&2)  continue; ry_pair(a[j],a[j|2] ,cB[7],sB[7]); }
    #pragma unroll
    for (int j=0;j<16;j++){ if (j&4)  continue; ry_pair(a[j],a[j|4] ,cB[8],sB[8]); }
    #pragma unroll
    for (int j=0;j<16;j++){ if (j&4) continue; if ((j>>3)&1){ float2 tm=a[j]; a[j]=a[j|4]; a[j|4]=tm; } } // (9->8)
    #pragma unroll
    for (int j=0;j<16;j++){ if (j&2) continue; if ((j>>2)&1){ float2 tm=a[j]; a[j]=a[j|2]; a[j|2]=tm; } } // (8->7)
    #pragma unroll
    for (int j=0;j<16;j++){ if (j&1) continue; if ((j>>1)&1){ float2 tm=a[j]; a[j]=a[j|1]; a[j|1]=tm; } } // (7->6)
    #pragma unroll
    for (int i=0;i<16;i++) a[i] = cmul(a[i], E2B[i&7]);      // Rz2(f6..8)
    #pragma unroll
    for (int j=0;j<16;j++){ if (j&2)  continue; ry_pair(a[j],a[j|2] ,cC[7],sC[7]); }
    #pragma unroll
    for (int j=0;j<16;j++){ if (j&4)  continue; ry_pair(a[j],a[j|4] ,cC[8],sC[8]); }
    #pragma unroll
    for (int j=0;j<16;j++){ if (j&8)  continue; ry_pair(a[j],a[j|8] ,cC[9],sC[9]); }
    // ---- transpose B -> C
    #pragma unroll
    for (int i=0;i<16;i++) tile[swz((t&63u) | ((unsigned)i<<6) | ((t>>6)<<10))] = a[i];
    __syncthreads();
    #pragma unroll
    for (int i=0;i<16;i++) a[i] = tile[swz((t&7u) | ((unsigned)i<<3) | ((t>>3)<<7))];
    // Trip C: i0=f3,i1=f4,i2=f5,i3=f6 ; t&7=f0..2, t>>3=f7..12
    #pragma unroll
    for (int j=0;j<16;j++){ if (j&1)  continue; ry_pair(a[j],a[j|1] ,cB[3],sB[3]); }
    #pragma unroll
    for (int j=0;j<16;j++){ if (j&2)  continue; ry_pair(a[j],a[j|2] ,cB[4],sB[4]); }
    #pragma unroll
    for (int j=0;j<16;j++){ if (j&4)  continue; ry_pair(a[j],a[j|4] ,cB[5],sB[5]); }
    #pragma unroll
    for (int j=0;j<16;j++){ if (j&4) continue; if ((j>>3)&1){ float2 tm=a[j]; a[j]=a[j|4]; a[j|4]=tm; } } // (6->5)
    #pragma unroll
    for (int j=0;j<16;j++){ if (j&2) continue; if ((j>>2)&1){ float2 tm=a[j]; a[j]=a[j|2]; a[j|2]=tm; } } // (5->4)
    #pragma unroll
    for (int j=0;j<16;j++){ if (j&1) continue; if ((j>>1)&1){ float2 tm=a[j]; a[j]=a[j|1]; a[j|1]=tm; } } // (4->3)
    #pragma unroll
    for (int i=0;i<16;i++) a[i] = cmul(a[i], E2C[i&7]);      // Rz2(f3..5)
    #pragma unroll
    for (int j=0;j<16;j++){ if (j&2)  continue; ry_pair(a[j],a[j|2] ,cC[4],sC[4]); }
    #pragma unroll
    for (int j=0;j<16;j++){ if (j&4)  continue; ry_pair(a[j],a[j|4] ,cC[5],sC[5]); }
    #pragma unroll
    for (int j=0;j<16;j++){ if (j&8)  continue; ry_pair(a[j],a[j|8] ,cC[6],sC[6]); }
    // ---- transpose C -> D
    #pragma unroll
    for (int i=0;i<16;i++) tile[swz((t&7u) | ((unsigned)i<<3) | ((t>>3)<<7))] = a[i];
    __syncthreads();
    #pragma unroll
    for (int i=0;i<16;i++) a[i] = tile[swz((unsigned)i | (t<<4))];
    // Trip D: i0=f0,i1=f1,i2=f2,i3=f3 ; t=f4..12
    #pragma unroll
    for (int j=0;j<16;j++){ if (j&1)  continue; ry_pair(a[j],a[j|1] ,cB[0],sB[0]); }
    #pragma unroll
    for (int j=0;j<16;j++){ if (j&2)  continue; ry_pair(a[j],a[j|2] ,cB[1],sB[1]); }
    #pragma unroll
    for (int j=0;j<16;j++){ if (j&4)  continue; ry_pair(a[j],a[j|4] ,cB[2],sB[2]); }
    #pragma unroll
    for (int j=0;j<16;j++){ if (j&4) continue; if ((j>>3)&1){ float2 tm=a[j]; a[j]=a[j|4]; a[j|4]=tm; } } // (3->2)
    #pragma unroll
    for (int j=0;j<16;j++){ if (j&2) continue; if ((j>>2)&1){ float2 tm=a[j]; a[j]=a[j|2]; a[j|2]=tm; } } // (2->1)
    #pragma unroll
    for (int j=0;j<16;j++){ if (j&1) continue; if ((j>>1)&1){ float2 tm=a[j]; a[j]=a[j|1]; a[j|1]=tm; } } // (1->0)
    #pragma unroll
    for (int i=0;i<16;i++) a[i] = cmul(a[i], E2D[i&7]);      // Rz2(f0..2,f13,f14)
    #pragma unroll
    for (int j=0;j<16;j++){ if (j&2)  continue; ry_pair(a[j],a[j|2] ,cC[1],sC[1]); }
    #pragma unroll
    for (int j=0;j<16;j++){ if (j&4)  continue; ry_pair(a[j],a[j|4] ,cC[2],sC[2]); }
    #pragma unroll
    for (int j=0;j<16;j++){ if (j&8)  continue; ry_pair(a[j],a[j|8] ,cC[3],sC[3]); }
    // ---- store transpose: write own D-cells, re-read densely, coalesced store.
    // NOTE: swz(idx+k) = swz(idx)^k for k<4 (idx bits 0-1 are zero; swz XORs
    // low-5 bits with bits 5-9, which +k does not touch).  R7 bug was sb0+k.
    #pragma unroll
    for (int i=0;i<16;i++) tile[swz((unsigned)i | (t<<4))] = a[i];
    __syncthreads();
    float2* sp = st + ((size_t)b<<16);
    #pragma unroll
    for (int u=0;u<4;u++){
        const unsigned idx = (t<<2) | ((unsigned)u<<11);     // 4 amps per u
        const unsigned sb0 = swz(idx);
        float2 v0=tile[sb0^0u], v1=tile[sb0^1u], v2=tile[sb0^2u], v3=tile[sb0^3u];
        float4* d4 = (float4*)(sp + (idx | (outer<<13)));
        d4[0]=make_float4(v0.x,v0.y,v1.x,v1.y);
        d4[1]=make_float4(v2.x,v2.y,v3.x,v3.y);
    }
}

// ---------------- P2 k_fin (B-type, outer = f10..12, READ, no LDS tile) — verbatim
__global__ __launch_bounds__(256) void k_fin(const float* __restrict__ xg,
                                             const float* __restrict__ pg,
                                             const float2* __restrict__ st,
                                             float* __restrict__ outg)
{
    __shared__ float cN[16], sN[16];
    __shared__ float snp, csp;
    __shared__ float red[4][3];
    const int tid = threadIdx.x;
    const int b = blockIdx.x >> 3;
    const unsigned outer = blockIdx.x & 7u;        // f bits 10..12
    if (tid < 16){
        int j=tid, q=15-j;
        float th = 0.5f*(xg[b*16+q]*PI_F + pg[64 + q]);      // Ry3
        float s,c; __sincosf(th,&s,&c);
        cN[j]=c; sN[j]=s;
    }
    if (tid==16){ float phi = 0.5f*pg[48 + 0]; float s,c; __sincosf(phi,&s,&c); snp=s; csp=c; }
    __syncthreads();
    const unsigned t = tid;
    const float2* sp = st + ((size_t)b<<16);
    float2 a[32];
    #pragma unroll
    for (int u=0;u<8;u++){
        unsigned fb = (t<<2) | (outer<<10) | ((unsigned)u<<13);
        const float4* s4 = (const float4*)(sp + fb);
        float4 v0=s4[0], v1=s4[1];
        a[4*u+0]=make_float2(v0.x,v0.y); a[4*u+1]=make_float2(v0.z,v0.w);
        a[4*u+2]=make_float2(v1.x,v1.y); a[4*u+3]=make_float2(v1.z,v1.w);
    }
    // CN2(0->15): ctrl f0 = i0, tgt f15 = i4
    #pragma unroll
    for (int j=0;j<32;j++){ if (j&16) continue; if (j&1){ float2 tm=a[j]; a[j]=a[j|16]; a[j|16]=tm; } }
    // Rz2(f15)
    #pragma unroll
    for (int j=0;j<32;j++){
        float sn = ((j>>4)&1)? snp : -snp;
        float2 v=a[j];
        a[j]=make_float2(v.x*csp - v.y*sn, v.x*sn + v.y*csp);
    }
    #pragma unroll
    for (int j=0;j<32;j++){ if (j&1)  continue; ry_pair(a[j],a[j|1] ,cN[0] ,sN[0]);  }
    #pragma unroll
    for (int j=0;j<32;j++){ if (j&4)  continue; ry_pair(a[j],a[j|4] ,cN[13],sN[13]); }
    #pragma unroll
    for (int j=0;j<32;j++){ if (j&8)  continue; ry_pair(a[j],a[j|8] ,cN[14],sN[14]); }
    #pragma unroll
    for (int j=0;j<32;j++){ if (j&16) continue; ry_pair(a[j],a[j|16],cN[15],sN[15]); }
    const int pto = (__popc(t) + __popc(outer)) & 1;   // parity(f2..f12)
    float v0=0.f, v1=0.f, v2=0.f;
    #pragma unroll
    for (int i=0;i<32;i++){
        const int i0=i&1, i1=(i>>1)&1, i2=(i>>2)&1, i3=(i>>3)&1, i4=(i>>4)&1;
        const float pr = a[i].x*a[i].x + a[i].y*a[i].y;
        v0 += (i0^i1^i2^i3^pto)? -pr : pr;   // parity(f0..f14)
        v1 += (i3^i4)?           -pr : pr;   // f14^f15
        v2 += (i2^i3^i4)?        -pr : pr;   // f13^f14^f15
    }
    #pragma unroll
    for (int off=32; off>0; off>>=1){
        v0 += __shfl_down(v0, off);
        v1 += __shfl_down(v1, off);
        v2 += __shfl_down(v2, off);
    }
    const int wv = tid>>6, ln = tid&63;
    if (ln==0){ red[wv][0]=v0; red[wv][1]=v1; red[wv][2]=v2; }
    __syncthreads();
    if (tid<3){
        float s = red[0][tid]+red[1][tid]+red[2][tid]+red[3][tid];
        atomicAdd(&outg[b*3+tid], s);
    }
}

extern "C" void kernel_launch(void* const* d_in, const int* in_sizes, int n_in,
                              void* d_out, int out_size, void* d_ws, size_t ws_size,
                              hipStream_t stream)
{
    const float* x = (const float*)d_in[0];
    const float* params = (const float*)d_in[1];
    float* out = (float*)d_out;
    float2* st = (float2*)d_ws;
    const int B = in_sizes[0] / 16;

    hipMemsetAsync(d_out, 0, (size_t)out_size*sizeof(float), stream);

    const size_t per = (size_t)65536 * sizeof(float2);   // 512 KB per batch element
    int chunk = (int)(ws_size / per);
    if (chunk > 256) chunk = 256;                        // 128 MB -> L3-resident handoff
    if (chunk < 1) chunk = 1;
    if (chunk > B) chunk = B;
    for (int b0=0; b0<B; b0+=chunk){
        const int nb = (B-b0 < chunk) ? (B-b0) : chunk;
        const float* xb = x + (size_t)b0*16;
        float* ob = out + (size_t)b0*3;
        hipLaunchKernelGGL(k_all, dim3(nb*8), dim3(512), 0, stream, xb, params, st);
        hipLaunchKernelGGL(k_fin, dim3(nb*8), dim3(256), 0, stream, xb, params, st, ob);
    }
}